// Round 11
// baseline (327.091 us; speedup 1.0000x reference)
//
#include <hip/hip_runtime.h>
#include <math.h>

#define D 64
#define NEG_SLOPE 0.2f
#define TILE 2048   // edges per partition block
#define BKT 128     // nodes per coarse bucket
#define LDK 72      // padded k-stride (bf16 elems) for MFMA LDS tiles
#define LDC 72      // padded col-stride (fp32) for epilogue C tile

typedef __attribute__((ext_vector_type(8))) short bf16x8;
typedef __attribute__((ext_vector_type(4))) float f32x4;

__device__ __forceinline__ float lrelu(float x) { return fmaxf(x, NEG_SLOPE * x); }

// fp32 -> bf16 round-to-nearest-even.
__device__ __forceinline__ unsigned short f2bf(float f) {
    unsigned u = __float_as_uint(f);
    return (unsigned short)((u + 0x7fffu + ((u >> 16) & 1u)) >> 16);
}

// w-splat fused multiply-add on a float4 vector; lowers to llvm.fma.v4f32 ->
// v_pk_fma_f32 pairs on gfx950.
__device__ __forceinline__ f32x4 fma4(const f32x4 h, const float w, const f32x4 c) {
    f32x4 wv = {w, w, w, w};
    return __builtin_elementwise_fma(h, wv, c);
}

// MFMA bf16 GEMM: h_f32 = x @ W (bf16 inputs, fp32 out) + fused alpha dot products.
// Block: 64 rows x 64 cols, 4 waves; wave w owns rows w*16..+15 (4 n-tiles x K=64).
__global__ __launch_bounds__(256) void gemm_alpha(
    const void* __restrict__ xin, int x_is_bf16,
    const float* __restrict__ W,
    const float* __restrict__ a_src, const float* __restrict__ a_dst,
    float* __restrict__ hf, float* __restrict__ asrc,
    float* __restrict__ adst, int N) {
    __shared__ union {
        struct { unsigned short xs[64 * LDK]; unsigned short wt[64 * LDK]; } s;
        float cs[64 * LDC];
    } u;
    const int tid = threadIdx.x;
    const int r0 = blockIdx.x * 64;

    // stage W[k][n] -> wt[n][k] bf16 (transposed, n-major)
    for (int i = tid; i < 1024; i += 256) {
        const int k = i >> 4, n0 = (i & 15) * 4;
        const float4 w4 = *(const float4*)&W[k * 64 + n0];
        u.s.wt[(n0 + 0) * LDK + k] = f2bf(w4.x);
        u.s.wt[(n0 + 1) * LDK + k] = f2bf(w4.y);
        u.s.wt[(n0 + 2) * LDK + k] = f2bf(w4.z);
        u.s.wt[(n0 + 3) * LDK + k] = f2bf(w4.w);
    }
    // stage x rows -> xs[r][k] bf16
    if (x_is_bf16) {
        const unsigned short* xb = (const unsigned short*)xin;
        for (int i = tid; i < 1024; i += 256) {
            const int r = i >> 4, c0 = (i & 15) * 4;
            const int gr = r0 + r;
            uint2 v = make_uint2(0u, 0u);
            if (gr < N) v = *(const uint2*)&xb[(size_t)gr * D + c0];
            *(uint2*)&u.s.xs[r * LDK + c0] = v;
        }
    } else {
        const float* xf = (const float*)xin;
        for (int i = tid; i < 1024; i += 256) {
            const int r = i >> 4, c0 = (i & 15) * 4;
            const int gr = r0 + r;
            float4 v = make_float4(0.f, 0.f, 0.f, 0.f);
            if (gr < N) v = *(const float4*)&xf[(size_t)gr * D + c0];
            unsigned short q[4] = {f2bf(v.x), f2bf(v.y), f2bf(v.z), f2bf(v.w)};
            *(uint2*)&u.s.xs[r * LDK + c0] = *(uint2*)q;
        }
    }
    __syncthreads();

    const int wv = tid >> 6, lane = tid & 63;
    const int m = lane & 15, quad = lane >> 4;
    const int rw = wv * 16;
    bf16x8 afr0 = *(const bf16x8*)&u.s.xs[(rw + m) * LDK + quad * 8];
    bf16x8 afr1 = *(const bf16x8*)&u.s.xs[(rw + m) * LDK + 32 + quad * 8];
    f32x4 acc[4];
#pragma unroll
    for (int nt = 0; nt < 4; ++nt) {
        f32x4 a = {0.f, 0.f, 0.f, 0.f};
        const bf16x8 b0 = *(const bf16x8*)&u.s.wt[(nt * 16 + m) * LDK + quad * 8];
        const bf16x8 b1 = *(const bf16x8*)&u.s.wt[(nt * 16 + m) * LDK + 32 + quad * 8];
        a = __builtin_amdgcn_mfma_f32_16x16x32_bf16(afr0, b0, a, 0, 0, 0);
        a = __builtin_amdgcn_mfma_f32_16x16x32_bf16(afr1, b1, a, 0, 0, 0);
        acc[nt] = a;
    }
    __syncthreads();  // staging dead; reuse union as C tile
#pragma unroll
    for (int nt = 0; nt < 4; ++nt)
#pragma unroll
        for (int reg = 0; reg < 4; ++reg)
            u.cs[(rw + quad * 4 + reg) * LDC + nt * 16 + m] = acc[nt][reg];
    __syncthreads();

    // epilogue: thread -> row r=tid>>2, 16-col segment; fp32 h store + alpha dots
    {
        const int r = tid >> 2, cseg = (tid & 3) * 16;
        const int gr = r0 + r;
        float vals[16];
#pragma unroll
        for (int q4 = 0; q4 < 4; ++q4)
            *(float4*)&vals[q4 * 4] = *(const float4*)&u.cs[r * LDC + cseg + q4 * 4];
        if (gr < N) {
#pragma unroll
            for (int q4 = 0; q4 < 4; ++q4)
                *(float4*)&hf[(size_t)gr * D + cseg + q4 * 4] = *(float4*)&vals[q4 * 4];
        }
        float ps = 0.f, pd = 0.f;
#pragma unroll
        for (int q4 = 0; q4 < 4; ++q4) {
            const float4 as4 = *(const float4*)&a_src[cseg + q4 * 4];
            const float4 ad4 = *(const float4*)&a_dst[cseg + q4 * 4];
            ps = fmaf(vals[q4 * 4 + 0], as4.x, ps); pd = fmaf(vals[q4 * 4 + 0], ad4.x, pd);
            ps = fmaf(vals[q4 * 4 + 1], as4.y, ps); pd = fmaf(vals[q4 * 4 + 1], ad4.y, pd);
            ps = fmaf(vals[q4 * 4 + 2], as4.z, ps); pd = fmaf(vals[q4 * 4 + 2], ad4.z, pd);
            ps = fmaf(vals[q4 * 4 + 3], as4.w, ps); pd = fmaf(vals[q4 * 4 + 3], ad4.w, pd);
        }
        ps += __shfl_xor(ps, 1); ps += __shfl_xor(ps, 2);
        pd += __shfl_xor(pd, 1); pd += __shfl_xor(pd, 2);
        if ((tid & 3) == 0 && gr < N) { asrc[gr] = ps; adst[gr] = pd; }
    }
}

// A.1: per-tile histogram over coarse buckets (d>>7). mat[b*nblkA + blk] = count.
__global__ void histA(const int* __restrict__ dst, int* __restrict__ mat,
                      int E, int nblkA, int NBc) {
    __shared__ int cnt[1024];
    for (int b = threadIdx.x; b < NBc; b += 256) cnt[b] = 0;
    __syncthreads();
    const int base = blockIdx.x * TILE;
    for (int j = threadIdx.x; j < TILE; j += 256) {
        int i = base + j;
        if (i < E) atomicAdd(&cnt[dst[i] >> 7], 1);
    }
    __syncthreads();
    for (int b = threadIdx.x; b < NBc; b += 256) mat[b * nblkA + blockIdx.x] = cnt[b];
}

// A.2: hierarchical exclusive scan of mat[0..M) in place (bucket-major).
__global__ void scan_part1(const int* __restrict__ a, int* __restrict__ bsum, int M) {
    __shared__ int s[4];
    const int lane = threadIdx.x & 63, wid = threadIdx.x >> 6;
    int base = blockIdx.x * 1024;
    int v = 0;
    for (int j = threadIdx.x; j < 1024; j += 256) {
        int i = base + j;
        v += (i < M) ? a[i] : 0;
    }
#pragma unroll
    for (int off = 32; off; off >>= 1) v += __shfl_xor(v, off);
    if (lane == 0) s[wid] = v;
    __syncthreads();
    if (threadIdx.x == 0) bsum[blockIdx.x] = s[0] + s[1] + s[2] + s[3];
}
__global__ void scan_part2(int* __restrict__ bsum, int nb) {
    const int lane = threadIdx.x;  // 64 threads
    int running = 0;
    for (int base = 0; base < nb; base += 64) {
        int i = base + lane;
        int v = (i < nb) ? bsum[i] : 0;
        int x = v;
#pragma unroll
        for (int off = 1; off < 64; off <<= 1) {
            int y = __shfl_up(x, off);
            if (lane >= off) x += y;
        }
        if (i < nb) bsum[i] = running + x - v;
        running += __shfl(x, 63);
    }
}
__global__ void scan_part3(int* __restrict__ a, const int* __restrict__ bsum, int M) {
    __shared__ int wsum[4];
    const int lane = threadIdx.x & 63, wid = threadIdx.x >> 6;
    const int i0 = blockIdx.x * 1024 + (int)threadIdx.x * 4;
    int v[4];
#pragma unroll
    for (int u = 0; u < 4; ++u) v[u] = (i0 + u < M) ? a[i0 + u] : 0;
    int tsum = v[0] + v[1] + v[2] + v[3];
    int incl = tsum;
#pragma unroll
    for (int off = 1; off < 64; off <<= 1) {
        int y = __shfl_up(incl, off);
        if (lane >= off) incl += y;
    }
    if (lane == 63) wsum[wid] = incl;
    __syncthreads();
    int woff = 0;
    for (int w = 0; w < wid; ++w) woff += wsum[w];
    int ex = bsum[blockIdx.x] + woff + incl - tsum;
#pragma unroll
    for (int u = 0; u < 4; ++u) {
        if (i0 + u < M) a[i0 + u] = ex;
        ex += v[u];
    }
}

// A.3: replay tile; write packed (d&127)<<17 | src into this block's contiguous
// per-bucket allocation (LDS cursors from scanned mat column).
__global__ void scatterA(const int* __restrict__ src, const int* __restrict__ dst,
                         const int* __restrict__ mat, unsigned* __restrict__ tmp,
                         int E, int nblkA, int NBc) {
    __shared__ int cur[1024];
    for (int b = threadIdx.x; b < NBc; b += 256) cur[b] = mat[b * nblkA + blockIdx.x];
    __syncthreads();
    const int base = blockIdx.x * TILE;
    for (int j = threadIdx.x; j < TILE; j += 256) {
        int i = base + j;
        if (i < E) {
            int d = dst[i];
            int pos = atomicAdd(&cur[d >> 7], 1);
            tmp[pos] = ((unsigned)(d & (BKT - 1)) << 17) | (unsigned)src[i];
        }
    }
}

// B: one block per coarse bucket (128 nodes). Builds row[] and places src into csr.
__global__ void bucket_build(const int* __restrict__ mat, const unsigned* __restrict__ tmp,
                             int* __restrict__ row, int* __restrict__ csr,
                             int N, int E, int nblkA, int NBc) {
    __shared__ int cnt[BKT];
    __shared__ int cur[BKT];
    __shared__ int wsumS[2];
    const int b = blockIdx.x;
    const int n0 = b << 7;
    const int tid = threadIdx.x;
    const int beg = mat[b * nblkA];
    const int end = (b + 1 < NBc) ? mat[(b + 1) * nblkA] : E;
    if (tid < BKT) cnt[tid] = 0;
    __syncthreads();
    for (int i = beg + tid; i < end; i += 256) atomicAdd(&cnt[tmp[i] >> 17], 1);
    __syncthreads();
    int v = (tid < BKT) ? cnt[tid] : 0;
    int x = v;
#pragma unroll
    for (int off = 1; off < 64; off <<= 1) {
        int y = __shfl_up(x, off);
        if ((tid & 63) >= off) x += y;
    }
    if (tid < BKT && (tid & 63) == 63) wsumS[tid >> 6] = x;
    __syncthreads();
    const int add = (tid >= 64 && tid < BKT) ? wsumS[0] : 0;
    const int ex = beg + add + x - v;
    if (tid < BKT) {
        const int node = n0 + tid;
        if (node < N) row[node] = ex;
        cur[tid] = ex;
    }
    if (b == NBc - 1 && tid == 0) row[N] = E;
    __syncthreads();
    for (int i = beg + tid; i < end; i += 256) {
        unsigned e = tmp[i];
        int pos = atomicAdd(&cur[e >> 17], 1);
        csr[pos] = (int)(e & 0x1FFFFu);
    }
}

// Aggregate: one node per 8-lane group (32 nodes/block). Lane owns 8 fp32
// features (two dwordx4 per row -> no bf16 unpack). f32x4 elementwise-fma
// lowers to v_pk_fma_f32 -> ~46% fewer inner-loop instructions than bf16 path
// (kernel is VALU-issue-bound: R5->R6 byte-halving slowed it, R8 instr cut won).
__global__ __launch_bounds__(256) void aggregate(
    const int* __restrict__ row, const int* __restrict__ csr_src,
    const float* __restrict__ asrc, const float* __restrict__ adst,
    const float* __restrict__ hf, const float* __restrict__ bias,
    void* __restrict__ outp, int N, int do_elu, int out_bf16) {
    const int g = threadIdx.x >> 3;
    const int c = threadIdx.x & 7;
    const int d = blockIdx.x * 32 + g;
    if (d >= N) return;
    const int beg = row[d], end = row[d + 1];
    const float ad = adst[d];
    float dnp = __expf(lrelu(asrc[d] + ad));

    const float* hrow = hf + (c << 3);  // lane's 32B slot within any row
    f32x4 acc0, acc1;
    {
        const float* p = hrow + ((size_t)d << 6);
        const f32x4 h0 = *(const f32x4*)p;
        const f32x4 h1 = *(const f32x4*)(p + 4);
        f32x4 wv = {dnp, dnp, dnp, dnp};
        acc0 = h0 * wv;
        acc1 = h1 * wv;
    }

    int i = beg;
    for (; i + 4 <= end; i += 4) {
        const int s0 = csr_src[i], s1 = csr_src[i + 1];
        const int s2 = csr_src[i + 2], s3 = csr_src[i + 3];
        const float a0 = asrc[s0], a1 = asrc[s1], a2 = asrc[s2], a3 = asrc[s3];
        const float* p0 = hrow + ((size_t)s0 << 6);
        const float* p1 = hrow + ((size_t)s1 << 6);
        const float* p2 = hrow + ((size_t)s2 << 6);
        const float* p3 = hrow + ((size_t)s3 << 6);
        const f32x4 h00 = *(const f32x4*)p0, h01 = *(const f32x4*)(p0 + 4);
        const f32x4 h10 = *(const f32x4*)p1, h11 = *(const f32x4*)(p1 + 4);
        const f32x4 h20 = *(const f32x4*)p2, h21 = *(const f32x4*)(p2 + 4);
        const f32x4 h30 = *(const f32x4*)p3, h31 = *(const f32x4*)(p3 + 4);
        const float w0 = __expf(lrelu(a0 + ad));
        const float w1 = __expf(lrelu(a1 + ad));
        const float w2 = __expf(lrelu(a2 + ad));
        const float w3 = __expf(lrelu(a3 + ad));
        dnp += (w0 + w1) + (w2 + w3);
        acc0 = fma4(h00, w0, acc0); acc1 = fma4(h01, w0, acc1);
        acc0 = fma4(h10, w1, acc0); acc1 = fma4(h11, w1, acc1);
        acc0 = fma4(h20, w2, acc0); acc1 = fma4(h21, w2, acc1);
        acc0 = fma4(h30, w3, acc0); acc1 = fma4(h31, w3, acc1);
    }
    for (; i < end; ++i) {
        const int s0 = csr_src[i];
        const float* p0 = hrow + ((size_t)s0 << 6);
        const f32x4 h00 = *(const f32x4*)p0, h01 = *(const f32x4*)(p0 + 4);
        const float w0 = __expf(lrelu(asrc[s0] + ad));
        dnp += w0;
        acc0 = fma4(h00, w0, acc0); acc1 = fma4(h01, w0, acc1);
    }

    const float inv = 1.f / dnp;
    const float4 b0 = *(const float4*)&bias[c << 3];
    const float4 b1 = *(const float4*)&bias[(c << 3) + 4];
    float v[8];
    v[0] = fmaf(acc0.x, inv, b0.x); v[1] = fmaf(acc0.y, inv, b0.y);
    v[2] = fmaf(acc0.z, inv, b0.z); v[3] = fmaf(acc0.w, inv, b0.w);
    v[4] = fmaf(acc1.x, inv, b1.x); v[5] = fmaf(acc1.y, inv, b1.y);
    v[6] = fmaf(acc1.z, inv, b1.z); v[7] = fmaf(acc1.w, inv, b1.w);
    if (do_elu) {
#pragma unroll
        for (int k = 0; k < 8; ++k) v[k] = v[k] > 0.f ? v[k] : expm1f(v[k]);
    }
    if (out_bf16) {
        unsigned pk[4];
#pragma unroll
        for (int j = 0; j < 4; ++j)
            pk[j] = (unsigned)f2bf(v[2 * j]) | ((unsigned)f2bf(v[2 * j + 1]) << 16);
        *(uint4*)((unsigned short*)outp + ((size_t)d << 6) + (c << 3)) = *(uint4*)pk;
    } else {
        float* out = (float*)outp;
        *(float4*)&out[((size_t)d << 6) + (c << 3)]     = *(float4*)&v[0];
        *(float4*)&out[((size_t)d << 6) + (c << 3) + 4] = *(float4*)&v[4];
    }
}

extern "C" void kernel_launch(void* const* d_in, const int* in_sizes, int n_in,
                              void* d_out, int out_size, void* d_ws, size_t ws_size,
                              hipStream_t stream) {
    const int*   eidx = (const int*)d_in[0];
    const float* emb  = (const float*)d_in[1];
    const float* W1   = (const float*)d_in[2];
    const float* a1s  = (const float*)d_in[3];
    const float* a1d  = (const float*)d_in[4];
    const float* b1   = (const float*)d_in[5];
    const float* W2   = (const float*)d_in[6];
    const float* a2s  = (const float*)d_in[7];
    const float* a2d  = (const float*)d_in[8];
    const float* b2   = (const float*)d_in[9];
    float* out = (float*)d_out;

    const int E = in_sizes[0] / 2;
    const int N = in_sizes[1] / D;  // requires N <= 131072 (17-bit src packing)
    const int* src = eidx;
    const int* dst = eidx + E;

    const int nblkA = (E + TILE - 1) / TILE;
    const int NBc   = (N + BKT - 1) / BKT;
    const int M     = NBc * nblkA;
    const int nscan = (M + 1023) / 1024;

    // Workspace: hf [N*D fp32], x1b [N*D bf16], asrc/adst [N], row [N+1],
    // mat [M], msum [nscan], csr [E]. tmp [E] aliases x1b (dead until L1 aggregate).
    float* hf = (float*)d_ws;
    unsigned short* x1b = (unsigned short*)(hf + (size_t)N * D);
    float* asrc = (float*)(x1b + (size_t)N * D);
    float* adst = asrc + N;
    int* row    = (int*)(adst + N);
    int* mat    = row + N + 1;
    int* msum   = mat + M;
    int* csr    = msum + nscan;
    unsigned* tmp = (unsigned*)x1b;

    const int gemmBlocks = (N + 63) / 64;
    const int aggBlocks  = (N + 31) / 32;

    // ---- CSR build ----
    histA<<<nblkA, 256, 0, stream>>>(dst, mat, E, nblkA, NBc);
    scan_part1<<<nscan, 256, 0, stream>>>(mat, msum, M);
    scan_part2<<<1, 64, 0, stream>>>(msum, nscan);
    scan_part3<<<nscan, 256, 0, stream>>>(mat, msum, M);
    scatterA<<<nblkA, 256, 0, stream>>>(src, dst, mat, tmp, E, nblkA, NBc);
    bucket_build<<<NBc, 256, 0, stream>>>(mat, tmp, row, csr, N, E, nblkA, NBc);

    // ---- Layer 1 ----
    gemm_alpha<<<gemmBlocks, 256, 0, stream>>>(emb, 0, W1, a1s, a1d, hf, asrc, adst, N);
    aggregate<<<aggBlocks, 256, 0, stream>>>(row, csr, asrc, adst, hf, b1, x1b, N, 1, 1);

    // ---- Layer 2 ----
    gemm_alpha<<<gemmBlocks, 256, 0, stream>>>(x1b, 1, W2, a2s, a2d, hf, asrc, adst, N);
    aggregate<<<aggBlocks, 256, 0, stream>>>(row, csr, asrc, adst, hf, b2, out, N, 0, 0);
}

// Round 12
// 257.244 us; speedup vs baseline: 1.2715x; 1.2715x over previous
//
#include <hip/hip_runtime.h>
#include <math.h>

#define D 64
#define NEG_SLOPE 0.2f
#define TILE 2048   // edges per partition block
#define BKT 128     // nodes per coarse bucket
#define LDK 72      // padded k-stride (bf16 elems) for MFMA LDS tiles
#define LDC 72      // padded col-stride (fp32) for epilogue C tile

typedef __attribute__((ext_vector_type(8))) short bf16x8;
typedef __attribute__((ext_vector_type(4))) float f32x4;
typedef __attribute__((ext_vector_type(2))) float f32x2;

__device__ __forceinline__ float lrelu(float x) { return fmaxf(x, NEG_SLOPE * x); }

// fp32 -> bf16 round-to-nearest-even.
__device__ __forceinline__ unsigned short f2bf(float f) {
    unsigned u = __float_as_uint(f);
    return (unsigned short)((u + 0x7fffu + ((u >> 16) & 1u)) >> 16);
}

// Packed bf16 pair -> f32x2 with ONE shift: hi half used raw (low 16 garbage
// bits = rel err < 2^-16, an order below bf16's own 2^-9 rounding noise).
__device__ __forceinline__ f32x2 bfpair(unsigned u) {
    f32x2 r;
    r.x = __uint_as_float(u << 16);
    r.y = __uint_as_float(u);
    return r;
}
// w-splat fma on a float2 -> v_pk_fma_f32.
__device__ __forceinline__ f32x2 fma2(const f32x2 h, const float w, const f32x2 c) {
    f32x2 wv = {w, w};
    return __builtin_elementwise_fma(h, wv, c);
}

// MFMA bf16 GEMM: h_bf16 = bf16(x @ W) + fused alpha_src/alpha_dst dot products.
// Block: 64 rows x 64 cols, 4 waves; wave w owns rows w*16..+15 (4 n-tiles x K=64).
__global__ __launch_bounds__(256) void gemm_alpha(
    const void* __restrict__ xin, int x_is_bf16,
    const float* __restrict__ W,
    const float* __restrict__ a_src, const float* __restrict__ a_dst,
    unsigned short* __restrict__ hb, float* __restrict__ asrc,
    float* __restrict__ adst, int N) {
    __shared__ union {
        struct { unsigned short xs[64 * LDK]; unsigned short wt[64 * LDK]; } s;
        float cs[64 * LDC];
    } u;
    const int tid = threadIdx.x;
    const int r0 = blockIdx.x * 64;

    // stage W[k][n] -> wt[n][k] bf16 (transposed, n-major)
    for (int i = tid; i < 1024; i += 256) {
        const int k = i >> 4, n0 = (i & 15) * 4;
        const float4 w4 = *(const float4*)&W[k * 64 + n0];
        u.s.wt[(n0 + 0) * LDK + k] = f2bf(w4.x);
        u.s.wt[(n0 + 1) * LDK + k] = f2bf(w4.y);
        u.s.wt[(n0 + 2) * LDK + k] = f2bf(w4.z);
        u.s.wt[(n0 + 3) * LDK + k] = f2bf(w4.w);
    }
    // stage x rows -> xs[r][k] bf16
    if (x_is_bf16) {
        const unsigned short* xb = (const unsigned short*)xin;
        for (int i = tid; i < 1024; i += 256) {
            const int r = i >> 4, c0 = (i & 15) * 4;
            const int gr = r0 + r;
            uint2 v = make_uint2(0u, 0u);
            if (gr < N) v = *(const uint2*)&xb[(size_t)gr * D + c0];
            *(uint2*)&u.s.xs[r * LDK + c0] = v;
        }
    } else {
        const float* xf = (const float*)xin;
        for (int i = tid; i < 1024; i += 256) {
            const int r = i >> 4, c0 = (i & 15) * 4;
            const int gr = r0 + r;
            float4 v = make_float4(0.f, 0.f, 0.f, 0.f);
            if (gr < N) v = *(const float4*)&xf[(size_t)gr * D + c0];
            unsigned short q[4] = {f2bf(v.x), f2bf(v.y), f2bf(v.z), f2bf(v.w)};
            *(uint2*)&u.s.xs[r * LDK + c0] = *(uint2*)q;
        }
    }
    __syncthreads();

    const int wv = tid >> 6, lane = tid & 63;
    const int m = lane & 15, quad = lane >> 4;
    const int rw = wv * 16;
    bf16x8 afr0 = *(const bf16x8*)&u.s.xs[(rw + m) * LDK + quad * 8];
    bf16x8 afr1 = *(const bf16x8*)&u.s.xs[(rw + m) * LDK + 32 + quad * 8];
    f32x4 acc[4];
#pragma unroll
    for (int nt = 0; nt < 4; ++nt) {
        f32x4 a = {0.f, 0.f, 0.f, 0.f};
        const bf16x8 b0 = *(const bf16x8*)&u.s.wt[(nt * 16 + m) * LDK + quad * 8];
        const bf16x8 b1 = *(const bf16x8*)&u.s.wt[(nt * 16 + m) * LDK + 32 + quad * 8];
        a = __builtin_amdgcn_mfma_f32_16x16x32_bf16(afr0, b0, a, 0, 0, 0);
        a = __builtin_amdgcn_mfma_f32_16x16x32_bf16(afr1, b1, a, 0, 0, 0);
        acc[nt] = a;
    }
    __syncthreads();  // staging dead; reuse union as C tile
#pragma unroll
    for (int nt = 0; nt < 4; ++nt)
#pragma unroll
        for (int reg = 0; reg < 4; ++reg)
            u.cs[(rw + quad * 4 + reg) * LDC + nt * 16 + m] = acc[nt][reg];
    __syncthreads();

    // epilogue: thread -> row r=tid>>2, 16-col segment; coalesced bf16 store + alpha dots
    {
        const int r = tid >> 2, cseg = (tid & 3) * 16;
        const int gr = r0 + r;
        float vals[16];
#pragma unroll
        for (int q4 = 0; q4 < 4; ++q4)
            *(float4*)&vals[q4 * 4] = *(const float4*)&u.cs[r * LDC + cseg + q4 * 4];
        if (gr < N) {
            unsigned pk[8];
#pragma unroll
            for (int j = 0; j < 8; ++j)
                pk[j] = (unsigned)f2bf(vals[2 * j]) | ((unsigned)f2bf(vals[2 * j + 1]) << 16);
            *(uint4*)&hb[(size_t)gr * D + cseg] = *(uint4*)&pk[0];
            *(uint4*)&hb[(size_t)gr * D + cseg + 8] = *(uint4*)&pk[4];
        }
        float ps = 0.f, pd = 0.f;
#pragma unroll
        for (int q4 = 0; q4 < 4; ++q4) {
            const float4 as4 = *(const float4*)&a_src[cseg + q4 * 4];
            const float4 ad4 = *(const float4*)&a_dst[cseg + q4 * 4];
            ps = fmaf(vals[q4 * 4 + 0], as4.x, ps); pd = fmaf(vals[q4 * 4 + 0], ad4.x, pd);
            ps = fmaf(vals[q4 * 4 + 1], as4.y, ps); pd = fmaf(vals[q4 * 4 + 1], ad4.y, pd);
            ps = fmaf(vals[q4 * 4 + 2], as4.z, ps); pd = fmaf(vals[q4 * 4 + 2], ad4.z, pd);
            ps = fmaf(vals[q4 * 4 + 3], as4.w, ps); pd = fmaf(vals[q4 * 4 + 3], ad4.w, pd);
        }
        ps += __shfl_xor(ps, 1); ps += __shfl_xor(ps, 2);
        pd += __shfl_xor(pd, 1); pd += __shfl_xor(pd, 2);
        if ((tid & 3) == 0 && gr < N) { asrc[gr] = ps; adst[gr] = pd; }
    }
}

// A.1: per-tile histogram over coarse buckets (d>>7). mat[b*nblkA + blk] = count.
__global__ void histA(const int* __restrict__ dst, int* __restrict__ mat,
                      int E, int nblkA, int NBc) {
    __shared__ int cnt[1024];
    for (int b = threadIdx.x; b < NBc; b += 256) cnt[b] = 0;
    __syncthreads();
    const int base = blockIdx.x * TILE;
    for (int j = threadIdx.x; j < TILE; j += 256) {
        int i = base + j;
        if (i < E) atomicAdd(&cnt[dst[i] >> 7], 1);
    }
    __syncthreads();
    for (int b = threadIdx.x; b < NBc; b += 256) mat[b * nblkA + blockIdx.x] = cnt[b];
}

// A.2: hierarchical exclusive scan of mat[0..M) in place (bucket-major).
__global__ void scan_part1(const int* __restrict__ a, int* __restrict__ bsum, int M) {
    __shared__ int s[4];
    const int lane = threadIdx.x & 63, wid = threadIdx.x >> 6;
    int base = blockIdx.x * 1024;
    int v = 0;
    for (int j = threadIdx.x; j < 1024; j += 256) {
        int i = base + j;
        v += (i < M) ? a[i] : 0;
    }
#pragma unroll
    for (int off = 32; off; off >>= 1) v += __shfl_xor(v, off);
    if (lane == 0) s[wid] = v;
    __syncthreads();
    if (threadIdx.x == 0) bsum[blockIdx.x] = s[0] + s[1] + s[2] + s[3];
}
__global__ void scan_part2(int* __restrict__ bsum, int nb) {
    const int lane = threadIdx.x;  // 64 threads
    int running = 0;
    for (int base = 0; base < nb; base += 64) {
        int i = base + lane;
        int v = (i < nb) ? bsum[i] : 0;
        int x = v;
#pragma unroll
        for (int off = 1; off < 64; off <<= 1) {
            int y = __shfl_up(x, off);
            if (lane >= off) x += y;
        }
        if (i < nb) bsum[i] = running + x - v;
        running += __shfl(x, 63);
    }
}
__global__ void scan_part3(int* __restrict__ a, const int* __restrict__ bsum, int M) {
    __shared__ int wsum[4];
    const int lane = threadIdx.x & 63, wid = threadIdx.x >> 6;
    const int i0 = blockIdx.x * 1024 + (int)threadIdx.x * 4;
    int v[4];
#pragma unroll
    for (int u = 0; u < 4; ++u) v[u] = (i0 + u < M) ? a[i0 + u] : 0;
    int tsum = v[0] + v[1] + v[2] + v[3];
    int incl = tsum;
#pragma unroll
    for (int off = 1; off < 64; off <<= 1) {
        int y = __shfl_up(incl, off);
        if (lane >= off) incl += y;
    }
    if (lane == 63) wsum[wid] = incl;
    __syncthreads();
    int woff = 0;
    for (int w = 0; w < wid; ++w) woff += wsum[w];
    int ex = bsum[blockIdx.x] + woff + incl - tsum;
#pragma unroll
    for (int u = 0; u < 4; ++u) {
        if (i0 + u < M) a[i0 + u] = ex;
        ex += v[u];
    }
}

// A.3: replay tile; write packed (d&127)<<17 | src into this block's contiguous
// per-bucket allocation (LDS cursors from scanned mat column).
__global__ void scatterA(const int* __restrict__ src, const int* __restrict__ dst,
                         const int* __restrict__ mat, unsigned* __restrict__ tmp,
                         int E, int nblkA, int NBc) {
    __shared__ int cur[1024];
    for (int b = threadIdx.x; b < NBc; b += 256) cur[b] = mat[b * nblkA + blockIdx.x];
    __syncthreads();
    const int base = blockIdx.x * TILE;
    for (int j = threadIdx.x; j < TILE; j += 256) {
        int i = base + j;
        if (i < E) {
            int d = dst[i];
            int pos = atomicAdd(&cur[d >> 7], 1);
            tmp[pos] = ((unsigned)(d & (BKT - 1)) << 17) | (unsigned)src[i];
        }
    }
}

// B: one block per coarse bucket (128 nodes). Builds row[] and places src into csr.
__global__ void bucket_build(const int* __restrict__ mat, const unsigned* __restrict__ tmp,
                             int* __restrict__ row, int* __restrict__ csr,
                             int N, int E, int nblkA, int NBc) {
    __shared__ int cnt[BKT];
    __shared__ int cur[BKT];
    __shared__ int wsumS[2];
    const int b = blockIdx.x;
    const int n0 = b << 7;
    const int tid = threadIdx.x;
    const int beg = mat[b * nblkA];
    const int end = (b + 1 < NBc) ? mat[(b + 1) * nblkA] : E;
    if (tid < BKT) cnt[tid] = 0;
    __syncthreads();
    for (int i = beg + tid; i < end; i += 256) atomicAdd(&cnt[tmp[i] >> 17], 1);
    __syncthreads();
    int v = (tid < BKT) ? cnt[tid] : 0;
    int x = v;
#pragma unroll
    for (int off = 1; off < 64; off <<= 1) {
        int y = __shfl_up(x, off);
        if ((tid & 63) >= off) x += y;
    }
    if (tid < BKT && (tid & 63) == 63) wsumS[tid >> 6] = x;
    __syncthreads();
    const int add = (tid >= 64 && tid < BKT) ? wsumS[0] : 0;
    const int ex = beg + add + x - v;
    if (tid < BKT) {
        const int node = n0 + tid;
        if (node < N) row[node] = ex;
        cur[tid] = ex;
    }
    if (b == NBc - 1 && tid == 0) row[N] = E;
    __syncthreads();
    for (int i = beg + tid; i < end; i += 256) {
        unsigned e = tmp[i];
        int pos = atomicAdd(&cur[e >> 17], 1);
        csr[pos] = (int)(e & 0x1FFFFu);
    }
}

// Aggregate: one node per 8-lane group (32 nodes/block). Lane owns 8 bf16
// features (one uint4). Unpack via bfpair (1 shift / 2 features, hi used raw)
// + f32x2 pk-fma: ~12 VALU/edge vs R9's ~20 at identical FETCH (bf16 h is the
// right byte/instr tradeoff: fp32 h regressed to L2-fill-bound, R10).
__global__ __launch_bounds__(256) void aggregate(
    const int* __restrict__ row, const int* __restrict__ csr_src,
    const float* __restrict__ asrc, const float* __restrict__ adst,
    const unsigned short* __restrict__ hb, const float* __restrict__ bias,
    void* __restrict__ outp, int N, int do_elu, int out_bf16) {
    const int g = threadIdx.x >> 3;
    const int c = threadIdx.x & 7;
    const int d = blockIdx.x * 32 + g;
    if (d >= N) return;
    const int beg = row[d], end = row[d + 1];
    const float ad = adst[d];
    float dnp = __expf(lrelu(asrc[d] + ad));

    const unsigned short* hrow = hb + (c << 3);  // lane's 16B slot within any row
    f32x2 acc0, acc1, acc2, acc3;
    {
        const uint4 hv = *(const uint4*)(hrow + ((unsigned)d << 6));
        f32x2 wv = {dnp, dnp};
        acc0 = bfpair(hv.x) * wv;
        acc1 = bfpair(hv.y) * wv;
        acc2 = bfpair(hv.z) * wv;
        acc3 = bfpair(hv.w) * wv;
    }

    int i = beg;
    for (; i + 4 <= end; i += 4) {
        const int s0 = csr_src[i], s1 = csr_src[i + 1];
        const int s2 = csr_src[i + 2], s3 = csr_src[i + 3];
        const float a0 = asrc[s0], a1 = asrc[s1], a2 = asrc[s2], a3 = asrc[s3];
        const uint4 h0 = *(const uint4*)(hrow + ((unsigned)s0 << 6));
        const uint4 h1 = *(const uint4*)(hrow + ((unsigned)s1 << 6));
        const uint4 h2 = *(const uint4*)(hrow + ((unsigned)s2 << 6));
        const uint4 h3 = *(const uint4*)(hrow + ((unsigned)s3 << 6));
        const float w0 = __expf(lrelu(a0 + ad));
        const float w1 = __expf(lrelu(a1 + ad));
        const float w2 = __expf(lrelu(a2 + ad));
        const float w3 = __expf(lrelu(a3 + ad));
        dnp += (w0 + w1) + (w2 + w3);
        acc0 = fma2(bfpair(h0.x), w0, acc0); acc1 = fma2(bfpair(h0.y), w0, acc1);
        acc2 = fma2(bfpair(h0.z), w0, acc2); acc3 = fma2(bfpair(h0.w), w0, acc3);
        acc0 = fma2(bfpair(h1.x), w1, acc0); acc1 = fma2(bfpair(h1.y), w1, acc1);
        acc2 = fma2(bfpair(h1.z), w1, acc2); acc3 = fma2(bfpair(h1.w), w1, acc3);
        acc0 = fma2(bfpair(h2.x), w2, acc0); acc1 = fma2(bfpair(h2.y), w2, acc1);
        acc2 = fma2(bfpair(h2.z), w2, acc2); acc3 = fma2(bfpair(h2.w), w2, acc3);
        acc0 = fma2(bfpair(h3.x), w3, acc0); acc1 = fma2(bfpair(h3.y), w3, acc1);
        acc2 = fma2(bfpair(h3.z), w3, acc2); acc3 = fma2(bfpair(h3.w), w3, acc3);
    }
    for (; i < end; ++i) {
        const int s0 = csr_src[i];
        const float w0 = __expf(lrelu(asrc[s0] + ad));
        const uint4 h0 = *(const uint4*)(hrow + ((unsigned)s0 << 6));
        dnp += w0;
        acc0 = fma2(bfpair(h0.x), w0, acc0); acc1 = fma2(bfpair(h0.y), w0, acc1);
        acc2 = fma2(bfpair(h0.z), w0, acc2); acc3 = fma2(bfpair(h0.w), w0, acc3);
    }

    const float inv = 1.f / dnp;
    const float4 b0 = *(const float4*)&bias[c << 3];
    const float4 b1 = *(const float4*)&bias[(c << 3) + 4];
    float v[8];
    v[0] = fmaf(acc0.x, inv, b0.x); v[1] = fmaf(acc0.y, inv, b0.y);
    v[2] = fmaf(acc1.x, inv, b0.z); v[3] = fmaf(acc1.y, inv, b0.w);
    v[4] = fmaf(acc2.x, inv, b1.x); v[5] = fmaf(acc2.y, inv, b1.y);
    v[6] = fmaf(acc3.x, inv, b1.z); v[7] = fmaf(acc3.y, inv, b1.w);
    if (do_elu) {
#pragma unroll
        for (int k = 0; k < 8; ++k) v[k] = v[k] > 0.f ? v[k] : expm1f(v[k]);
    }
    if (out_bf16) {
        unsigned pk[4];
#pragma unroll
        for (int j = 0; j < 4; ++j)
            pk[j] = (unsigned)f2bf(v[2 * j]) | ((unsigned)f2bf(v[2 * j + 1]) << 16);
        *(uint4*)((unsigned short*)outp + ((size_t)d << 6) + (c << 3)) = *(uint4*)pk;
    } else {
        float* out = (float*)outp;
        *(float4*)&out[((size_t)d << 6) + (c << 3)]     = *(float4*)&v[0];
        *(float4*)&out[((size_t)d << 6) + (c << 3) + 4] = *(float4*)&v[4];
    }
}

extern "C" void kernel_launch(void* const* d_in, const int* in_sizes, int n_in,
                              void* d_out, int out_size, void* d_ws, size_t ws_size,
                              hipStream_t stream) {
    const int*   eidx = (const int*)d_in[0];
    const float* emb  = (const float*)d_in[1];
    const float* W1   = (const float*)d_in[2];
    const float* a1s  = (const float*)d_in[3];
    const float* a1d  = (const float*)d_in[4];
    const float* b1   = (const float*)d_in[5];
    const float* W2   = (const float*)d_in[6];
    const float* a2s  = (const float*)d_in[7];
    const float* a2d  = (const float*)d_in[8];
    const float* b2   = (const float*)d_in[9];
    float* out = (float*)d_out;

    const int E = in_sizes[0] / 2;
    const int N = in_sizes[1] / D;  // requires N <= 131072 (17-bit src packing)
    const int* src = eidx;
    const int* dst = eidx + E;

    const int nblkA = (E + TILE - 1) / TILE;
    const int NBc   = (N + BKT - 1) / BKT;
    const int M     = NBc * nblkA;
    const int nscan = (M + 1023) / 1024;

    // Workspace: hb [N*D bf16], x1b [N*D bf16], asrc/adst [N], row [N+1],
    // mat [M], msum [nscan], csr [E]. tmp [E] aliases x1b (dead until L1 aggregate).
    unsigned short* hb  = (unsigned short*)d_ws;
    unsigned short* x1b = hb + (size_t)N * D;
    float* asrc = (float*)(x1b + (size_t)N * D);
    float* adst = asrc + N;
    int* row    = (int*)(adst + N);
    int* mat    = row + N + 1;
    int* msum   = mat + M;
    int* csr    = msum + nscan;
    unsigned* tmp = (unsigned*)x1b;

    const int gemmBlocks = (N + 63) / 64;
    const int aggBlocks  = (N + 31) / 32;

    // ---- CSR build ----
    histA<<<nblkA, 256, 0, stream>>>(dst, mat, E, nblkA, NBc);
    scan_part1<<<nscan, 256, 0, stream>>>(mat, msum, M);
    scan_part2<<<1, 64, 0, stream>>>(msum, nscan);
    scan_part3<<<nscan, 256, 0, stream>>>(mat, msum, M);
    scatterA<<<nblkA, 256, 0, stream>>>(src, dst, mat, tmp, E, nblkA, NBc);
    bucket_build<<<NBc, 256, 0, stream>>>(mat, tmp, row, csr, N, E, nblkA, NBc);

    // ---- Layer 1 ----
    gemm_alpha<<<gemmBlocks, 256, 0, stream>>>(emb, 0, W1, a1s, a1d, hb, asrc, adst, N);
    aggregate<<<aggBlocks, 256, 0, stream>>>(row, csr, asrc, adst, hb, b1, x1b, N, 1, 1);

    // ---- Layer 2 ----
    gemm_alpha<<<gemmBlocks, 256, 0, stream>>>(x1b, 1, W2, a2s, a2d, hb, asrc, adst, N);
    aggregate<<<aggBlocks, 256, 0, stream>>>(row, csr, asrc, adst, hb, b2, out, N, 0, 0);
}